// Round 23
// baseline (246.678 us; speedup 1.0000x reference)
//
#include <hip/hip_runtime.h>

#define NROWS 65536   // B*T
#define DIM   256
#define VCB   2048
#define DELTA 0.25f   // pass-1 ambiguity margin (~23 sigma of hi-only d error)

typedef _Float16 f16;
typedef _Float16 f16x8 __attribute__((ext_vector_type(8)));
typedef float    f32x4 __attribute__((ext_vector_type(4)));

// ---------------- ws layout (bytes) ----------------
// [0,        262144)  idx        int[NROWS]
// [262144,   270336)  hist       uint[VCB]
// [270336,   272384)  loss_part  double[256]
// [272384,   280576)  enorm      float[VCB]
// [280576,   280580)  flag_cnt   int
// [524288,  1572864)  e_hi       f16[VCB*DIM]
// [1572864, 2621440)  e_lo       f16[VCB*DIM]
// d_out z_q region scratch (dead until gather): pval float[1M], pidx int[1M],
// flag_list int[65536] at out+32.

__device__ __forceinline__ void async16(void* lds, const void* g) {
  __builtin_amdgcn_global_load_lds(
      (const __attribute__((address_space(1))) void*)g,
      (__attribute__((address_space(3))) void*)lds, 16, 0, 0);
}

// fp32 -> (f16 hi, f16 lo) split — codebook only
__global__ __launch_bounds__(256) void convert_kernel(
    const float4* __restrict__ src, short4* __restrict__ dhi,
    short4* __restrict__ dlo, int n4) {
  int stride = gridDim.x * 256;
  for (int i = blockIdx.x * 256 + threadIdx.x; i < n4; i += stride) {
    float4 v = src[i];
    union { f16 h[4]; short4 s; } H, L;
    H.h[0] = (f16)v.x; H.h[1] = (f16)v.y; H.h[2] = (f16)v.z; H.h[3] = (f16)v.w;
    L.h[0] = (f16)(v.x - (float)H.h[0]);
    L.h[1] = (f16)(v.y - (float)H.h[1]);
    L.h[2] = (f16)(v.z - (float)H.h[2]);
    L.h[3] = (f16)(v.w - (float)H.h[3]);
    dhi[i] = H.s; dlo[i] = L.s;
  }
}

// zero hist + loss partials + flag counter, compute ||e_j||^2
__global__ __launch_bounds__(256) void prep_kernel(
    const float* __restrict__ e, float* __restrict__ enorm,
    unsigned int* __restrict__ hist, double* __restrict__ loss_part,
    int* __restrict__ flag_cnt) {
  int tid = threadIdx.x;
  int gt = blockIdx.x * 256 + tid;
  if (gt == 0) flag_cnt[0] = 0;
  if (gt < VCB) hist[gt] = 0u;
  if (gt < 256) loss_part[gt] = 0.0;
  int wid  = gt >> 6;
  int lane = tid & 63;
  if (wid < VCB) {
    const float4* row = (const float4*)(e + (size_t)wid * DIM);
    float4 v = row[lane];
    float s = v.x*v.x + v.y*v.y + v.z*v.z + v.w*v.w;
    #pragma unroll
    for (int off = 32; off; off >>= 1) s += __shfl_xor(s, off);
    if (lane == 0) enorm[wid] = s;
  }
}

// PASS 1 — hi-only MFMA distance GEMM + row (min1,idx1,min2) tracking.
// BK=128 MEGA-PHASES: 16 phases/block (r22 had 64; occupancy A/B proved
// TLP doesn't hide the ~2K cyc/phase serial sync cost, so amortize it).
// A (z hi) resident 32KB; B = 256c x 128k = 64KB, DOUBLE-buffered = 128KB;
// total exactly 160KB LDS, 1 block/CU. Per phase: vmcnt(0) [stage(p) landed,
// issued a full phase ago -> ~free]; barrier; stage(p+1) [WAR-safe: buf was
// read at p-1, behind this barrier]; 32 MFMA + 24 ds_reads per wave.
// Rows with min2-min1 <= DELTA flagged for exact pass 2; others final here.
__global__ __launch_bounds__(512) void pass1_kernel(
    const float* __restrict__ z, const f16* __restrict__ eh,
    const float* __restrict__ enorm,
    int* __restrict__ idx_out, unsigned int* __restrict__ hist,
    double* __restrict__ loss_part,
    int* __restrict__ flag_cnt, int* __restrict__ flag_list) {
  __shared__ f16 ldsA[8][2048];      // [kt][64 rows][32 k] hi, 32 KB
  __shared__ f16 ldsB[2][32768];     // [buf][4 ks][256 c][32 k] hi, 128 KB

  const int tid  = threadIdx.x;
  const int wid  = tid >> 6;
  const int lane = tid & 63;
  const int wr   = wid >> 2;        // 0..1 (32-row strip)
  const int wc   = wid & 3;         // 0..3 (64-col strip within 256)
  const int lrow = lane & 15;
  const int lq   = lane >> 4;
  const int rbase = blockIdx.x * 64;

  // stage one B mega-tile (256 cols x 128 k hi = 64 KB): 8 issues/thread.
  // Each wave-issue writes ONE contiguous 1KB span (base + lane*16B, the
  // global_load_lds dest rule); global source pre-swizzled to mirror reads.
  auto stageB = [&](int b, int ss, int kh) {
    #pragma unroll
    for (int ks = 0; ks < 4; ++ks) {
      #pragma unroll
      for (int i = 0; i < 2; ++i) {
        int col   = wid * 32 + i * 16 + (lane >> 2);  // 0..255
        int chunk = lane & 3;
        int gk    = chunk ^ ((col >> 1) & 3);
        size_t goff = (size_t)(ss * 256 + col) * DIM + kh * 128 + ks * 32 + (gk << 3);
        async16(&ldsB[b][ks * 8192] + col * 32 + chunk * 8, eh + goff);
      }
    }
  };

  // prologue: z fp32 -> hi split -> swizzled ds_write; accumulate z^2.
  // thread covers row=tid>>3 (0..63), kt=tid&7 (32 cols), 8 float4 loads.
  {
    const int row = tid >> 3;
    const int q   = tid & 7;        // = kt
    const float* zrow = z + (size_t)(rbase + row) * DIM + q * 32;
    const int sw = (row >> 1) & 3;
    float zs = 0.f;
    #pragma unroll
    for (int f = 0; f < 8; ++f) {
      float4 v = *(const float4*)(zrow + f * 4);
      int chunk  = f >> 1;
      int within = (f & 1) * 8;
      int addr = q * 4096 + row * 64 + ((chunk ^ sw) << 4) + within;
      union { f16 h[4]; short4 s4; } H;
      H.h[0] = (f16)v.x; H.h[1] = (f16)v.y; H.h[2] = (f16)v.z; H.h[3] = (f16)v.w;
      *(short4*)((char*)ldsA + addr) = H.s4;
      zs += v.x*v.x + v.y*v.y + v.z*v.z + v.w*v.w;
    }
    #pragma unroll
    for (int off = 32; off; off >>= 1) zs += __shfl_xor(zs, off);
    if (lane == 0) atomicAdd(&loss_part[blockIdx.x & 255], (double)zs);
  }
  __syncthreads();   // A resident (drains lgkmcnt properly)
  stageB(0, 0, 0);   // phase 0's B in flight

  float m1[2][4], m2v[2][4];
  int   i1[2][4];
  #pragma unroll
  for (int m = 0; m < 2; ++m)
    #pragma unroll
    for (int r = 0; r < 4; ++r) { m1[m][r] = 3.4e38f; m2v[m][r] = 3.4e38f; i1[m][r] = 0; }

  const int cchunk = lq ^ ((lrow >> 1) & 3);

  f32x4 acc[2][4];
  for (int p = 0; p < 16; ++p) {
    const int ss = p >> 1, kh = p & 1;
    const int pb = p & 1;
    if (kh == 0) {
      #pragma unroll
      for (int m = 0; m < 2; ++m)
        #pragma unroll
        for (int n = 0; n < 4; ++n) {
          f32x4 zz = {0.f, 0.f, 0.f, 0.f};
          acc[m][n] = zz;
        }
    }

    // RAW: my stage(p) loads landed (issued a full phase ago -> cheap drain)
    asm volatile("s_waitcnt vmcnt(0)" ::: "memory");
    // block-wide: everyone's stage(p) landed AND compute(p-1) reads done
    asm volatile("s_barrier" ::: "memory");
    __builtin_amdgcn_sched_barrier(0);
    // WAR-safe: buf[(p+1)&1] was last read at phase p-1, behind this barrier
    if (p + 1 < 16) stageB(pb ^ 1, (p + 1) >> 1, (p + 1) & 1);

    #pragma unroll
    for (int ks = 0; ks < 4; ++ks) {
      const char* abase = (const char*)ldsA + (kh * 4 + ks) * 4096;
      f16x8 ah[2];
      #pragma unroll
      for (int m = 0; m < 2; ++m) {
        int row = wr * 32 + m * 16 + lrow;
        ah[m] = *(const f16x8*)(abase + row * 64 + cchunk * 16);
      }
      const char* bbase = (const char*)&ldsB[pb][ks * 8192];
      #pragma unroll
      for (int n = 0; n < 4; ++n) {
        int col = wc * 64 + n * 16 + lrow;
        f16x8 bh = *(const f16x8*)(bbase + col * 64 + cchunk * 16);
        #pragma unroll
        for (int m = 0; m < 2; ++m)
          acc[m][n] = __builtin_amdgcn_mfma_f32_16x16x32_f16(ah[m], bh, acc[m][n], 0, 0, 0);
      }
    }

    if (kh == 1) {
      // epilogue this 256-col superstep: C/D col=lane&15, row=(lane>>4)*4+reg
      #pragma unroll
      for (int n = 0; n < 4; ++n) {
        int j = ss * 256 + wc * 64 + n * 16 + lrow;
        float en = enorm[j];
        #pragma unroll
        for (int m = 0; m < 2; ++m)
          #pragma unroll
          for (int r = 0; r < 4; ++r) {
            float s = fmaf(-2.f, acc[m][n][r], en);
            if (s < m1[m][r]) { m2v[m][r] = m1[m][r]; m1[m][r] = s; i1[m][r] = j; }
            else if (s < m2v[m][r]) m2v[m][r] = s;
          }
      }
    }
  }

  // 16-lane butterfly merge of (m1,i1,m2) — disjoint sets at every level
  #pragma unroll
  for (int off = 1; off < 16; off <<= 1) {
    #pragma unroll
    for (int m = 0; m < 2; ++m)
      #pragma unroll
      for (int r = 0; r < 4; ++r) {
        float o1 = __shfl_xor(m1[m][r], off);
        int   oi = __shfl_xor(i1[m][r], off);
        float o2 = __shfl_xor(m2v[m][r], off);
        float nm2 = fminf(fminf(m2v[m][r], o2), fmaxf(m1[m][r], o1));
        if (o1 < m1[m][r] || (o1 == m1[m][r] && oi < i1[m][r])) {
          m1[m][r] = o1; i1[m][r] = oi;
        }
        m2v[m][r] = nm2;
      }
  }

  // cross-wc merge (disjoint col sets); scratch ALIASES ldsB (all reads done)
  __syncthreads();
  float* sx1 = (float*)&ldsB[0][0];        // [3][2][32]
  float* sx2 = sx1 + 3 * 2 * 32;
  int*   sxi = (int*)(sx2 + 3 * 2 * 32);
  if (wc != 0 && lrow == 0) {
    #pragma unroll
    for (int m = 0; m < 2; ++m)
      #pragma unroll
      for (int r = 0; r < 4; ++r) {
        int li = m * 16 + lq * 4 + r;          // 0..31
        int ix = ((wc - 1) * 2 + wr) * 32 + li;
        sx1[ix] = m1[m][r];
        sx2[ix] = m2v[m][r];
        sxi[ix] = i1[m][r];
      }
  }
  __syncthreads();
  if (wc == 0 && lrow == 0) {
    float lsum = 0.f;
    #pragma unroll
    for (int m = 0; m < 2; ++m)
      #pragma unroll
      for (int r = 0; r < 4; ++r) {
        int li = m * 16 + lq * 4 + r;
        float v  = m1[m][r];
        int   bi = i1[m][r];
        float v2 = m2v[m][r];
        #pragma unroll
        for (int g = 0; g < 3; ++g) {
          int ix = (g * 2 + wr) * 32 + li;
          float ov = sx1[ix];
          float o2 = sx2[ix];
          int   oi = sxi[ix];
          float nm2 = fminf(fminf(v2, o2), fmaxf(v, ov));
          if (ov < v || (ov == v && oi < bi)) { v = ov; bi = oi; }
          v2 = nm2;
        }
        int row = rbase + wr * 32 + li;
        if (v2 - v <= DELTA) {
          int p = atomicAdd(flag_cnt, 1);
          flag_list[p] = row;
        } else {
          idx_out[row] = bi;
          atomicAdd(&hist[bi], 1u);
          lsum += v;                // v = d_min - ||z_row||^2 (hi-only approx)
        }
      }
    lsum += __shfl_xor(lsum, 16);
    lsum += __shfl_xor(lsum, 32);
    if (lane == 0) atomicAdd(&loss_part[blockIdx.x & 255], (double)lsum);
  }
}

// PASS 2a — exact 3-GEMM rescan of flagged rows, candidate-split 16 ways.
__global__ __launch_bounds__(512) void pass2_kernel(
    const float* __restrict__ z,
    const f16* __restrict__ eh, const f16* __restrict__ el,
    const float* __restrict__ enorm,
    const int* __restrict__ flag_cnt, const int* __restrict__ flag_list,
    float* __restrict__ pval, int* __restrict__ pidx) {
  __shared__ f16 ldsA[8][8192];   // [kt][hi 8KB | lo 8KB], 128 KB
  __shared__ f16 ldsB[2][8192];   // 32 KB dbuf (merge aliases)

  const int tid  = threadIdx.x;
  const int wid  = tid >> 6;
  const int lane = tid & 63;
  const int wr   = wid >> 2;
  const int wc   = wid & 3;
  const int lrow = lane & 15;
  const int lq   = lane >> 4;
  const int srow = tid >> 2;
  const int scol = tid & 3;
  const int skoff = ((scol ^ ((srow >> 1) & 3)) << 3);
  const int cchunk = lq ^ ((lrow >> 1) & 3);
  const int cnt = *flag_cnt;

  auto stageB = [&](int b, int vcol, int kt) {   // 2 loads/thread, lane*16B ✓
    size_t off = (size_t)(vcol + srow) * DIM + (kt << 5) + skoff;
    async16(&ldsB[b][0]    + tid * 8, eh + off);
    async16(&ldsB[b][4096] + tid * 8, el + off);
  };

  for (int job = blockIdx.x; ; job += gridDim.x) {
    int chunk = job >> 4, cb = job & 15;
    int base = chunk * 128;
    if (base >= cnt) break;
    int nrows = cnt - base; if (nrows > 128) nrows = 128;

    __syncthreads();   // prior job's LDS (incl. aliased merge) retired

    {
      const int row = tid >> 2;
      const int q   = tid & 3;
      int grow = flag_list[base + (row < nrows ? row : 0)];
      const float* zrow = z + (size_t)grow * DIM + q * 64;
      const int sw = (row >> 1) & 3;
      #pragma unroll
      for (int f = 0; f < 16; ++f) {
        float4 v = *(const float4*)(zrow + f * 4);
        int col4   = q * 64 + f * 4;
        int kt     = col4 >> 5;
        int ko     = col4 & 31;
        int chunk2 = ko >> 3;
        int within = (ko & 7) * 2;
        int addr = kt * 16384 + row * 64 + ((chunk2 ^ sw) << 4) + within;
        union { f16 h[4]; short4 s4; } H, L;
        H.h[0] = (f16)v.x; H.h[1] = (f16)v.y; H.h[2] = (f16)v.z; H.h[3] = (f16)v.w;
        L.h[0] = (f16)(v.x - (float)H.h[0]);
        L.h[1] = (f16)(v.y - (float)H.h[1]);
        L.h[2] = (f16)(v.z - (float)H.h[2]);
        L.h[3] = (f16)(v.w - (float)H.h[3]);
        *(short4*)((char*)ldsA + addr)        = H.s4;
        *(short4*)((char*)ldsA + addr + 8192) = L.s4;
      }
    }
    int pb = 0;
    stageB(0, cb * 128, 0);
    asm volatile("s_waitcnt vmcnt(0)" ::: "memory");
    __syncthreads();

    float minv[4][4];
    int   mini[4][4];
    #pragma unroll
    for (int m = 0; m < 4; ++m)
      #pragma unroll
      for (int r = 0; r < 4; ++r) { minv[m][r] = 3.4e38f; mini[m][r] = 0; }

    f32x4 acc[4][2];
    #pragma unroll
    for (int m = 0; m < 4; ++m)
      #pragma unroll
      for (int n = 0; n < 2; ++n) {
        f32x4 zz = {0.f, 0.f, 0.f, 0.f};
        acc[m][n] = zz;
      }

    for (int kt = 0; kt < 8; ++kt) {
      if (kt < 7) {
        stageB(pb ^ 1, cb * 128, kt + 1);
        asm volatile("s_waitcnt vmcnt(2)" ::: "memory");
      } else {
        asm volatile("s_waitcnt vmcnt(0)" ::: "memory");
      }
      asm volatile("s_barrier" ::: "memory");
      __builtin_amdgcn_sched_barrier(0);

      const char* abase = (const char*)&ldsA[kt][0];
      f16x8 ah[4], al[4];
      #pragma unroll
      for (int m = 0; m < 4; ++m) {
        int row = wr * 64 + m * 16 + lrow;
        int off = row * 64 + cchunk * 16;
        ah[m] = *(const f16x8*)(abase + off);
        al[m] = *(const f16x8*)(abase + 8192 + off);
      }
      const char* bbase = (const char*)&ldsB[pb][0];
      #pragma unroll
      for (int n = 0; n < 2; ++n) {
        int col = wc * 32 + n * 16 + lrow;
        int off = col * 64 + cchunk * 16;
        f16x8 bh = *(const f16x8*)(bbase + off);
        f16x8 bl = *(const f16x8*)(bbase + 8192 + off);
        #pragma unroll
        for (int m = 0; m < 4; ++m) {
          acc[m][n] = __builtin_amdgcn_mfma_f32_16x16x32_f16(ah[m], bh, acc[m][n], 0, 0, 0);
          acc[m][n] = __builtin_amdgcn_mfma_f32_16x16x32_f16(ah[m], bl, acc[m][n], 0, 0, 0);
          acc[m][n] = __builtin_amdgcn_mfma_f32_16x16x32_f16(al[m], bh, acc[m][n], 0, 0, 0);
        }
      }
      __builtin_amdgcn_sched_barrier(0);
      asm volatile("s_barrier" ::: "memory");
      pb ^= 1;
    }

    #pragma unroll
    for (int n = 0; n < 2; ++n) {
      int j = cb * 128 + wc * 32 + n * 16 + lrow;
      float en = enorm[j];
      #pragma unroll
      for (int m = 0; m < 4; ++m)
        #pragma unroll
        for (int r = 0; r < 4; ++r) {
          float s = fmaf(-2.f, acc[m][n][r], en);
          if (s < minv[m][r]) { minv[m][r] = s; mini[m][r] = j; }
        }
    }

    #pragma unroll
    for (int off = 1; off < 16; off <<= 1) {
      #pragma unroll
      for (int m = 0; m < 4; ++m)
        #pragma unroll
        for (int r = 0; r < 4; ++r) {
          float ov = __shfl_xor(minv[m][r], off);
          int   oi = __shfl_xor(mini[m][r], off);
          if (ov < minv[m][r] || (ov == minv[m][r] && oi < mini[m][r])) {
            minv[m][r] = ov; mini[m][r] = oi;
          }
        }
    }

    __syncthreads();
    float* sxv = (float*)&ldsB[0][0];          // [3][2][64]
    int*   sxi2 = (int*)(sxv + 3 * 2 * 64);
    if (wc != 0 && lrow == 0) {
      #pragma unroll
      for (int m = 0; m < 4; ++m)
        #pragma unroll
        for (int r = 0; r < 4; ++r) {
          int li = m * 16 + lq * 4 + r;
          int ix = ((wc - 1) * 2 + wr) * 64 + li;
          sxv[ix] = minv[m][r];
          sxi2[ix] = mini[m][r];
        }
    }
    __syncthreads();
    if (wc == 0 && lrow == 0) {
      #pragma unroll
      for (int m = 0; m < 4; ++m)
        #pragma unroll
        for (int r = 0; r < 4; ++r) {
          int li = m * 16 + lq * 4 + r;
          float v  = minv[m][r];
          int   bi = mini[m][r];
          #pragma unroll
          for (int g = 0; g < 3; ++g) {
            int ix = (g * 2 + wr) * 64 + li;
            float ov = sxv[ix];
            int   oi = sxi2[ix];
            if (ov < v || (ov == v && oi < bi)) { v = ov; bi = oi; }
          }
          int i = wr * 64 + li;
          if (i < nrows) {
            int fi = base + i;
            pval[fi * 16 + cb] = v;
            pidx[fi * 16 + cb] = bi;
          }
        }
    }
  }
}

// PASS 2b — merge 16 candidate-block partials per flagged row
__global__ __launch_bounds__(256) void pass2m_kernel(
    const int* __restrict__ flag_cnt, const int* __restrict__ flag_list,
    const float* __restrict__ pval, const int* __restrict__ pidx,
    int* __restrict__ idx_out, unsigned int* __restrict__ hist,
    double* __restrict__ loss_part) {
  int cnt = *flag_cnt;
  int t = blockIdx.x * 256 + threadIdx.x;
  int stride = gridDim.x * 256;
  for (int fi = t; fi < cnt; fi += stride) {
    float m = 3.4e38f; int bi = 0;
    #pragma unroll
    for (int cb = 0; cb < 16; ++cb) {
      float v = pval[fi * 16 + cb];
      int  ix = pidx[fi * 16 + cb];
      if (v < m || (v == m && ix < bi)) { m = v; bi = ix; }
    }
    int row = flag_list[fi];
    idx_out[row] = bi;
    atomicAdd(&hist[bi], 1u);
    atomicAdd(&loss_part[fi & 255], (double)m);
  }
}

// gather z_q = e[idx] (exact fp32), write z_q_st + float indices
__global__ __launch_bounds__(256) void gather_kernel(
    const float* __restrict__ e, const int* __restrict__ idx,
    float* __restrict__ zq_out, float* __restrict__ idxf_out) {
  int tid  = threadIdx.x;
  int w    = tid >> 6;
  int lane = tid & 63;
  int n    = blockIdx.x * 4 + w;

  int ci = idx[n];
  const float4* er = (const float4*)(e + (size_t)ci * DIM);
  ((float4*)(zq_out + (size_t)n * DIM))[lane] = er[lane];
  if (lane == 0) idxf_out[n] = (float)ci;
}

__global__ __launch_bounds__(256) void finalize_kernel(
    const unsigned int* __restrict__ hist, const double* __restrict__ loss_part,
    float* __restrict__ out) {
  __shared__ double lsh[4];
  __shared__ float  hsh[4];
  __shared__ float  denom_sh;
  int tid = threadIdx.x, lane = tid & 63, w = tid >> 6;

  float hs = 0.f;
  for (int j = tid; j < VCB; j += 256) hs += (float)hist[j];
  double ls = loss_part[tid];
  #pragma unroll
  for (int off = 32; off; off >>= 1) {
    hs += __shfl_xor(hs, off);
    ls += __shfl_xor(ls, off);
  }
  if (lane == 0) { lsh[w] = ls; hsh[w] = hs; }
  __syncthreads();
  if (tid == 0) {
    double lt = lsh[0] + lsh[1] + lsh[2] + lsh[3];
    float  ht = hsh[0] + hsh[1] + hsh[2] + hsh[3];
    out[0] = (float)(lt / (double)((size_t)NROWS * DIM));
    denom_sh = ht + 1e-8f;
  }
  __syncthreads();
  float denom = denom_sh;
  float* prob = out + 1 + (size_t)NROWS * DIM + NROWS;
  for (int j = tid; j < VCB; j += 256) prob[j] = (float)hist[j] / denom;
}

extern "C" void kernel_launch(void* const* d_in, const int* in_sizes, int n_in,
                              void* d_out, int out_size, void* d_ws, size_t ws_size,
                              hipStream_t stream) {
  (void)in_sizes; (void)n_in; (void)out_size; (void)ws_size;
  const float* z = (const float*)d_in[0];
  const float* e = (const float*)d_in[1];
  float* out = (float*)d_out;
  char*  ws  = (char*)d_ws;

  int*          idx       = (int*)ws;
  unsigned int* hist      = (unsigned int*)(ws + 262144);
  double*       loss_part = (double*)(ws + 270336);
  float*        enorm     = (float*)(ws + 272384);
  int*          flag_cnt  = (int*)(ws + 280576);
  f16*          e_hi      = (f16*)(ws + 524288);
  f16*          e_lo      = (f16*)(ws + 1572864);

  // pass-2 scratch in d_out's z_q region (dead until gather)
  float* pval      = out + 32;
  int*   pidx      = (int*)(out + 32 + 1048576);
  int*   flag_list = (int*)(out + 32 + 2097152);

  float* out_zq  = out + 1;
  float* out_idx = out + 1 + (size_t)NROWS * DIM;

  convert_kernel<<<128, 256, 0, stream>>>(
      (const float4*)e, (short4*)e_hi, (short4*)e_lo, VCB * DIM / 4);
  prep_kernel<<<512, 256, 0, stream>>>(e, enorm, hist, loss_part, flag_cnt);
  pass1_kernel<<<NROWS / 64, 512, 0, stream>>>(
      z, e_hi, enorm, idx, hist, loss_part, flag_cnt, flag_list);
  pass2_kernel<<<512, 512, 0, stream>>>(
      z, e_hi, e_lo, enorm, flag_cnt, flag_list, pval, pidx);
  pass2m_kernel<<<64, 256, 0, stream>>>(
      flag_cnt, flag_list, pval, pidx, idx, hist, loss_part);
  gather_kernel<<<NROWS / 4, 256, 0, stream>>>(e, idx, out_zq, out_idx);
  finalize_kernel<<<1, 256, 0, stream>>>(hist, loss_part, out);
}

// Round 24
// 207.595 us; speedup vs baseline: 1.1883x; 1.1883x over previous
//
#include <hip/hip_runtime.h>

#define NROWS 65536   // B*T
#define DIM   256
#define VCB   2048
#define DELTA 0.25f   // pass-1 ambiguity margin (~23 sigma of hi-only d error)

typedef _Float16 f16;
typedef _Float16 f16x8 __attribute__((ext_vector_type(8)));
typedef float    f32x4 __attribute__((ext_vector_type(4)));

// ---------------- ws layout (bytes) ----------------
// [0,        262144)  idx        int[NROWS]
// [262144,   270336)  hist       uint[VCB]
// [270336,   272384)  loss_part  double[256]
// [272384,   280576)  enorm      float[VCB]
// [280576,   280580)  flag_cnt   int
// [524288,  1572864)  e_hi       f16[VCB*DIM]
// [1572864, 2621440)  e_lo       f16[VCB*DIM]
// d_out z_q region scratch (dead until gather): pval float[1M], pidx int[1M],
// flag_list int[65536] at out+32.

__device__ __forceinline__ void async16(void* lds, const void* g) {
  __builtin_amdgcn_global_load_lds(
      (const __attribute__((address_space(1))) void*)g,
      (__attribute__((address_space(3))) void*)lds, 16, 0, 0);
}

// prep: zero hist/loss/flag, compute ||e_j||^2 AND convert e -> (hi,lo) f16
// (fused: one wave per codebook row; each lane owns 4 elems -> short4 stores)
__global__ __launch_bounds__(256) void prep_kernel(
    const float* __restrict__ e, float* __restrict__ enorm,
    short4* __restrict__ ehi4, short4* __restrict__ elo4,
    unsigned int* __restrict__ hist, double* __restrict__ loss_part,
    int* __restrict__ flag_cnt) {
  int tid = threadIdx.x;
  int gt = blockIdx.x * 256 + tid;
  if (gt == 0) flag_cnt[0] = 0;
  if (gt < VCB) hist[gt] = 0u;
  if (gt < 256) loss_part[gt] = 0.0;
  int wid  = gt >> 6;
  int lane = tid & 63;
  if (wid < VCB) {
    const float4* row = (const float4*)(e + (size_t)wid * DIM);
    float4 v = row[lane];
    union { f16 h[4]; short4 s; } H, L;
    H.h[0] = (f16)v.x; H.h[1] = (f16)v.y; H.h[2] = (f16)v.z; H.h[3] = (f16)v.w;
    L.h[0] = (f16)(v.x - (float)H.h[0]);
    L.h[1] = (f16)(v.y - (float)H.h[1]);
    L.h[2] = (f16)(v.z - (float)H.h[2]);
    L.h[3] = (f16)(v.w - (float)H.h[3]);
    ehi4[(size_t)wid * 64 + lane] = H.s;
    elo4[(size_t)wid * 64 + lane] = L.s;
    float s = v.x*v.x + v.y*v.y + v.z*v.z + v.w*v.w;
    #pragma unroll
    for (int off = 32; off; off >>= 1) s += __shfl_xor(s, off);
    if (lane == 0) enorm[wid] = s;
  }
}

// PASS 1 — hi-only MFMA distance GEMM + row (min1,idx1,min2) tracking.
// r22 verified configuration (pass1 = 168us, the measured structure floor):
// BM=64, A (z hi) resident 32KB + B triple-buffered 16KB tiles = 80KB LDS
// -> 2 blocks/CU. ONE barrier per phase (3-buffer WAR-safe). Wave tile
// 32x64. Rows with min2-min1 <= DELTA flagged for exact pass 2.
__global__ __launch_bounds__(512) void pass1_kernel(
    const float* __restrict__ z, const f16* __restrict__ eh,
    const float* __restrict__ enorm,
    int* __restrict__ idx_out, unsigned int* __restrict__ hist,
    double* __restrict__ loss_part,
    int* __restrict__ flag_cnt, int* __restrict__ flag_list) {
  __shared__ f16 ldsA[8][2048];    // [kt][64 rows][32 k] hi, 32 KB
  __shared__ f16 ldsB[3][8192];    // [buf][256 c][32 k] hi, 48 KB

  const int tid  = threadIdx.x;
  const int wid  = tid >> 6;
  const int lane = tid & 63;
  const int wr   = wid >> 2;        // 0..1 (32-row strip)
  const int wc   = wid & 3;         // 0..3 (64-col strip within 256)
  const int lrow = lane & 15;
  const int lq   = lane >> 4;
  const int rbase = blockIdx.x * 64;

  // stage one B tile (256 cols x 32 k hi = 16 KB): 2 issues/thread.
  // Each wave-issue writes ONE contiguous 1KB span (base + lane*16B, the
  // global_load_lds dest rule); global source pre-swizzled to mirror reads.
  auto stageB = [&](int b, int ss, int kt) {
    #pragma unroll
    for (int i = 0; i < 2; ++i) {
      int col   = wid * 32 + i * 16 + (lane >> 2);  // 0..255
      int chunk = lane & 3;
      int gk    = chunk ^ ((col >> 1) & 3);
      size_t goff = (size_t)(ss * 256 + col) * DIM + (kt << 5) + (gk << 3);
      async16(&ldsB[b][0] + col * 32 + chunk * 8, eh + goff);
    }
  };

  // prologue: z fp32 -> hi split -> swizzled ds_write; accumulate z^2.
  {
    const int row = tid >> 3;
    const int q   = tid & 7;        // = kt
    const float* zrow = z + (size_t)(rbase + row) * DIM + q * 32;
    const int sw = (row >> 1) & 3;
    float zs = 0.f;
    #pragma unroll
    for (int f = 0; f < 8; ++f) {
      float4 v = *(const float4*)(zrow + f * 4);
      int chunk  = f >> 1;
      int within = (f & 1) * 8;
      int addr = q * 4096 + row * 64 + ((chunk ^ sw) << 4) + within;
      union { f16 h[4]; short4 s4; } H;
      H.h[0] = (f16)v.x; H.h[1] = (f16)v.y; H.h[2] = (f16)v.z; H.h[3] = (f16)v.w;
      *(short4*)((char*)ldsA + addr) = H.s4;
      zs += v.x*v.x + v.y*v.y + v.z*v.z + v.w*v.w;
    }
    #pragma unroll
    for (int off = 32; off; off >>= 1) zs += __shfl_xor(zs, off);
    if (lane == 0) atomicAdd(&loss_part[blockIdx.x & 255], (double)zs);
  }
  stageB(0, 0, 0);
  asm volatile("s_waitcnt vmcnt(0)" ::: "memory");
  __syncthreads();   // A + B(0) resident

  float m1[2][4], m2v[2][4];
  int   i1[2][4];
  #pragma unroll
  for (int m = 0; m < 2; ++m)
    #pragma unroll
    for (int r = 0; r < 4; ++r) { m1[m][r] = 3.4e38f; m2v[m][r] = 3.4e38f; i1[m][r] = 0; }

  const int cchunk = lq ^ ((lrow >> 1) & 3);

  int pb = 0;
  for (int ss = 0; ss < 8; ++ss) {
    f32x4 acc[2][4];
    #pragma unroll
    for (int m = 0; m < 2; ++m)
      #pragma unroll
      for (int n = 0; n < 4; ++n) {
        f32x4 zz = {0.f, 0.f, 0.f, 0.f};
        acc[m][n] = zz;
      }

    for (int kt = 0; kt < 8; ++kt) {
      // stage phase p+1 into the 3rd buffer (single-barrier WAR-safe)
      int nkt = kt + 1, nss = ss;
      if (nkt == 8) { nkt = 0; ++nss; if (nss == 8) nss = 0; }  // tail: dummy
      int nxt = pb + 1; if (nxt == 3) nxt = 0;
      stageB(nxt, nss, nkt);
      asm volatile("s_waitcnt vmcnt(2)" ::: "memory");  // phase p's B landed
      asm volatile("s_barrier" ::: "memory");
      __builtin_amdgcn_sched_barrier(0);

      const char* abase = (const char*)ldsA + kt * 4096;
      f16x8 ah[2];
      #pragma unroll
      for (int m = 0; m < 2; ++m) {
        int row = wr * 32 + m * 16 + lrow;
        ah[m] = *(const f16x8*)(abase + row * 64 + cchunk * 16);
      }
      const char* bbase = (const char*)&ldsB[pb][0];
      #pragma unroll
      for (int n = 0; n < 4; ++n) {
        int col = wc * 64 + n * 16 + lrow;
        f16x8 bh = *(const f16x8*)(bbase + col * 64 + cchunk * 16);
        #pragma unroll
        for (int m = 0; m < 2; ++m)
          acc[m][n] = __builtin_amdgcn_mfma_f32_16x16x32_f16(ah[m], bh, acc[m][n], 0, 0, 0);
      }
      pb = nxt;
    }

    // epilogue this 256-col superstep: C/D col=lane&15, row=(lane>>4)*4+reg
    #pragma unroll
    for (int n = 0; n < 4; ++n) {
      int j = ss * 256 + wc * 64 + n * 16 + lrow;
      float en = enorm[j];
      #pragma unroll
      for (int m = 0; m < 2; ++m)
        #pragma unroll
        for (int r = 0; r < 4; ++r) {
          float s = fmaf(-2.f, acc[m][n][r], en);
          if (s < m1[m][r]) { m2v[m][r] = m1[m][r]; m1[m][r] = s; i1[m][r] = j; }
          else if (s < m2v[m][r]) m2v[m][r] = s;
        }
    }
  }
  asm volatile("s_waitcnt vmcnt(0)" ::: "memory");  // drain tail dummy stage

  // 16-lane butterfly merge of (m1,i1,m2) — disjoint sets at every level
  #pragma unroll
  for (int off = 1; off < 16; off <<= 1) {
    #pragma unroll
    for (int m = 0; m < 2; ++m)
      #pragma unroll
      for (int r = 0; r < 4; ++r) {
        float o1 = __shfl_xor(m1[m][r], off);
        int   oi = __shfl_xor(i1[m][r], off);
        float o2 = __shfl_xor(m2v[m][r], off);
        float nm2 = fminf(fminf(m2v[m][r], o2), fmaxf(m1[m][r], o1));
        if (o1 < m1[m][r] || (o1 == m1[m][r] && oi < i1[m][r])) {
          m1[m][r] = o1; i1[m][r] = oi;
        }
        m2v[m][r] = nm2;
      }
  }

  // cross-wc merge (disjoint col sets); scratch ALIASES ldsB (drained above)
  __syncthreads();
  float* sx1 = (float*)&ldsB[0][0];        // [3][2][32]
  float* sx2 = sx1 + 3 * 2 * 32;
  int*   sxi = (int*)(sx2 + 3 * 2 * 32);
  if (wc != 0 && lrow == 0) {
    #pragma unroll
    for (int m = 0; m < 2; ++m)
      #pragma unroll
      for (int r = 0; r < 4; ++r) {
        int li = m * 16 + lq * 4 + r;          // 0..31
        int ix = ((wc - 1) * 2 + wr) * 32 + li;
        sx1[ix] = m1[m][r];
        sx2[ix] = m2v[m][r];
        sxi[ix] = i1[m][r];
      }
  }
  __syncthreads();
  if (wc == 0 && lrow == 0) {
    float lsum = 0.f;
    #pragma unroll
    for (int m = 0; m < 2; ++m)
      #pragma unroll
      for (int r = 0; r < 4; ++r) {
        int li = m * 16 + lq * 4 + r;
        float v  = m1[m][r];
        int   bi = i1[m][r];
        float v2 = m2v[m][r];
        #pragma unroll
        for (int g = 0; g < 3; ++g) {
          int ix = (g * 2 + wr) * 32 + li;
          float ov = sx1[ix];
          float o2 = sx2[ix];
          int   oi = sxi[ix];
          float nm2 = fminf(fminf(v2, o2), fmaxf(v, ov));
          if (ov < v || (ov == v && oi < bi)) { v = ov; bi = oi; }
          v2 = nm2;
        }
        int row = rbase + wr * 32 + li;
        if (v2 - v <= DELTA) {
          int p = atomicAdd(flag_cnt, 1);
          flag_list[p] = row;
        } else {
          idx_out[row] = bi;
          atomicAdd(&hist[bi], 1u);
          lsum += v;                // v = d_min - ||z_row||^2 (hi-only approx)
        }
      }
    lsum += __shfl_xor(lsum, 16);
    lsum += __shfl_xor(lsum, 32);
    if (lane == 0) atomicAdd(&loss_part[blockIdx.x & 255], (double)lsum);
  }
}

// PASS 2a — exact 3-GEMM rescan of flagged rows, candidate-split 16 ways.
__global__ __launch_bounds__(512) void pass2_kernel(
    const float* __restrict__ z,
    const f16* __restrict__ eh, const f16* __restrict__ el,
    const float* __restrict__ enorm,
    const int* __restrict__ flag_cnt, const int* __restrict__ flag_list,
    float* __restrict__ pval, int* __restrict__ pidx) {
  __shared__ f16 ldsA[8][8192];   // [kt][hi 8KB | lo 8KB], 128 KB
  __shared__ f16 ldsB[2][8192];   // 32 KB dbuf (merge aliases)

  const int tid  = threadIdx.x;
  const int wid  = tid >> 6;
  const int lane = tid & 63;
  const int wr   = wid >> 2;
  const int wc   = wid & 3;
  const int lrow = lane & 15;
  const int lq   = lane >> 4;
  const int srow = tid >> 2;
  const int scol = tid & 3;
  const int skoff = ((scol ^ ((srow >> 1) & 3)) << 3);
  const int cchunk = lq ^ ((lrow >> 1) & 3);
  const int cnt = *flag_cnt;

  auto stageB = [&](int b, int vcol, int kt) {   // 2 loads/thread, lane*16B ✓
    size_t off = (size_t)(vcol + srow) * DIM + (kt << 5) + skoff;
    async16(&ldsB[b][0]    + tid * 8, eh + off);
    async16(&ldsB[b][4096] + tid * 8, el + off);
  };

  for (int job = blockIdx.x; ; job += gridDim.x) {
    int chunk = job >> 4, cb = job & 15;
    int base = chunk * 128;
    if (base >= cnt) break;
    int nrows = cnt - base; if (nrows > 128) nrows = 128;

    __syncthreads();   // prior job's LDS (incl. aliased merge) retired

    {
      const int row = tid >> 2;
      const int q   = tid & 3;
      int grow = flag_list[base + (row < nrows ? row : 0)];
      const float* zrow = z + (size_t)grow * DIM + q * 64;
      const int sw = (row >> 1) & 3;
      #pragma unroll
      for (int f = 0; f < 16; ++f) {
        float4 v = *(const float4*)(zrow + f * 4);
        int col4   = q * 64 + f * 4;
        int kt     = col4 >> 5;
        int ko     = col4 & 31;
        int chunk2 = ko >> 3;
        int within = (ko & 7) * 2;
        int addr = kt * 16384 + row * 64 + ((chunk2 ^ sw) << 4) + within;
        union { f16 h[4]; short4 s4; } H, L;
        H.h[0] = (f16)v.x; H.h[1] = (f16)v.y; H.h[2] = (f16)v.z; H.h[3] = (f16)v.w;
        L.h[0] = (f16)(v.x - (float)H.h[0]);
        L.h[1] = (f16)(v.y - (float)H.h[1]);
        L.h[2] = (f16)(v.z - (float)H.h[2]);
        L.h[3] = (f16)(v.w - (float)H.h[3]);
        *(short4*)((char*)ldsA + addr)        = H.s4;
        *(short4*)((char*)ldsA + addr + 8192) = L.s4;
      }
    }
    int pb = 0;
    stageB(0, cb * 128, 0);
    asm volatile("s_waitcnt vmcnt(0)" ::: "memory");
    __syncthreads();

    float minv[4][4];
    int   mini[4][4];
    #pragma unroll
    for (int m = 0; m < 4; ++m)
      #pragma unroll
      for (int r = 0; r < 4; ++r) { minv[m][r] = 3.4e38f; mini[m][r] = 0; }

    f32x4 acc[4][2];
    #pragma unroll
    for (int m = 0; m < 4; ++m)
      #pragma unroll
      for (int n = 0; n < 2; ++n) {
        f32x4 zz = {0.f, 0.f, 0.f, 0.f};
        acc[m][n] = zz;
      }

    for (int kt = 0; kt < 8; ++kt) {
      if (kt < 7) {
        stageB(pb ^ 1, cb * 128, kt + 1);
        asm volatile("s_waitcnt vmcnt(2)" ::: "memory");
      } else {
        asm volatile("s_waitcnt vmcnt(0)" ::: "memory");
      }
      asm volatile("s_barrier" ::: "memory");
      __builtin_amdgcn_sched_barrier(0);

      const char* abase = (const char*)&ldsA[kt][0];
      f16x8 ah[4], al[4];
      #pragma unroll
      for (int m = 0; m < 4; ++m) {
        int row = wr * 64 + m * 16 + lrow;
        int off = row * 64 + cchunk * 16;
        ah[m] = *(const f16x8*)(abase + off);
        al[m] = *(const f16x8*)(abase + 8192 + off);
      }
      const char* bbase = (const char*)&ldsB[pb][0];
      #pragma unroll
      for (int n = 0; n < 2; ++n) {
        int col = wc * 32 + n * 16 + lrow;
        int off = col * 64 + cchunk * 16;
        f16x8 bh = *(const f16x8*)(bbase + off);
        f16x8 bl = *(const f16x8*)(bbase + 8192 + off);
        #pragma unroll
        for (int m = 0; m < 4; ++m) {
          acc[m][n] = __builtin_amdgcn_mfma_f32_16x16x32_f16(ah[m], bh, acc[m][n], 0, 0, 0);
          acc[m][n] = __builtin_amdgcn_mfma_f32_16x16x32_f16(ah[m], bl, acc[m][n], 0, 0, 0);
          acc[m][n] = __builtin_amdgcn_mfma_f32_16x16x32_f16(al[m], bh, acc[m][n], 0, 0, 0);
        }
      }
      __builtin_amdgcn_sched_barrier(0);
      asm volatile("s_barrier" ::: "memory");
      pb ^= 1;
    }

    #pragma unroll
    for (int n = 0; n < 2; ++n) {
      int j = cb * 128 + wc * 32 + n * 16 + lrow;
      float en = enorm[j];
      #pragma unroll
      for (int m = 0; m < 4; ++m)
        #pragma unroll
        for (int r = 0; r < 4; ++r) {
          float s = fmaf(-2.f, acc[m][n][r], en);
          if (s < minv[m][r]) { minv[m][r] = s; mini[m][r] = j; }
        }
    }

    #pragma unroll
    for (int off = 1; off < 16; off <<= 1) {
      #pragma unroll
      for (int m = 0; m < 4; ++m)
        #pragma unroll
        for (int r = 0; r < 4; ++r) {
          float ov = __shfl_xor(minv[m][r], off);
          int   oi = __shfl_xor(mini[m][r], off);
          if (ov < minv[m][r] || (ov == minv[m][r] && oi < mini[m][r])) {
            minv[m][r] = ov; mini[m][r] = oi;
          }
        }
    }

    __syncthreads();
    float* sxv = (float*)&ldsB[0][0];          // [3][2][64]
    int*   sxi2 = (int*)(sxv + 3 * 2 * 64);
    if (wc != 0 && lrow == 0) {
      #pragma unroll
      for (int m = 0; m < 4; ++m)
        #pragma unroll
        for (int r = 0; r < 4; ++r) {
          int li = m * 16 + lq * 4 + r;
          int ix = ((wc - 1) * 2 + wr) * 64 + li;
          sxv[ix] = minv[m][r];
          sxi2[ix] = mini[m][r];
        }
    }
    __syncthreads();
    if (wc == 0 && lrow == 0) {
      #pragma unroll
      for (int m = 0; m < 4; ++m)
        #pragma unroll
        for (int r = 0; r < 4; ++r) {
          int li = m * 16 + lq * 4 + r;
          float v  = minv[m][r];
          int   bi = mini[m][r];
          #pragma unroll
          for (int g = 0; g < 3; ++g) {
            int ix = (g * 2 + wr) * 64 + li;
            float ov = sxv[ix];
            int   oi = sxi2[ix];
            if (ov < v || (ov == v && oi < bi)) { v = ov; bi = oi; }
          }
          int i = wr * 64 + li;
          if (i < nrows) {
            int fi = base + i;
            pval[fi * 16 + cb] = v;
            pidx[fi * 16 + cb] = bi;
          }
        }
    }
  }
}

// PASS 2b — merge 16 candidate-block partials per flagged row
__global__ __launch_bounds__(256) void pass2m_kernel(
    const int* __restrict__ flag_cnt, const int* __restrict__ flag_list,
    const float* __restrict__ pval, const int* __restrict__ pidx,
    int* __restrict__ idx_out, unsigned int* __restrict__ hist,
    double* __restrict__ loss_part) {
  int cnt = *flag_cnt;
  int t = blockIdx.x * 256 + threadIdx.x;
  int stride = gridDim.x * 256;
  for (int fi = t; fi < cnt; fi += stride) {
    float m = 3.4e38f; int bi = 0;
    #pragma unroll
    for (int cb = 0; cb < 16; ++cb) {
      float v = pval[fi * 16 + cb];
      int  ix = pidx[fi * 16 + cb];
      if (v < m || (v == m && ix < bi)) { m = v; bi = ix; }
    }
    int row = flag_list[fi];
    idx_out[row] = bi;
    atomicAdd(&hist[bi], 1u);
    atomicAdd(&loss_part[fi & 255], (double)m);
  }
}

// gather z_q = e[idx] (exact fp32), write z_q_st + float indices
__global__ __launch_bounds__(256) void gather_kernel(
    const float* __restrict__ e, const int* __restrict__ idx,
    float* __restrict__ zq_out, float* __restrict__ idxf_out) {
  int tid  = threadIdx.x;
  int w    = tid >> 6;
  int lane = tid & 63;
  int n    = blockIdx.x * 4 + w;

  int ci = idx[n];
  const float4* er = (const float4*)(e + (size_t)ci * DIM);
  ((float4*)(zq_out + (size_t)n * DIM))[lane] = er[lane];
  if (lane == 0) idxf_out[n] = (float)ci;
}

__global__ __launch_bounds__(256) void finalize_kernel(
    const unsigned int* __restrict__ hist, const double* __restrict__ loss_part,
    float* __restrict__ out) {
  __shared__ double lsh[4];
  __shared__ float  hsh[4];
  __shared__ float  denom_sh;
  int tid = threadIdx.x, lane = tid & 63, w = tid >> 6;

  float hs = 0.f;
  for (int j = tid; j < VCB; j += 256) hs += (float)hist[j];
  double ls = loss_part[tid];
  #pragma unroll
  for (int off = 32; off; off >>= 1) {
    hs += __shfl_xor(hs, off);
    ls += __shfl_xor(ls, off);
  }
  if (lane == 0) { lsh[w] = ls; hsh[w] = hs; }
  __syncthreads();
  if (tid == 0) {
    double lt = lsh[0] + lsh[1] + lsh[2] + lsh[3];
    float  ht = hsh[0] + hsh[1] + hsh[2] + hsh[3];
    out[0] = (float)(lt / (double)((size_t)NROWS * DIM));
    denom_sh = ht + 1e-8f;
  }
  __syncthreads();
  float denom = denom_sh;
  float* prob = out + 1 + (size_t)NROWS * DIM + NROWS;
  for (int j = tid; j < VCB; j += 256) prob[j] = (float)hist[j] / denom;
}

extern "C" void kernel_launch(void* const* d_in, const int* in_sizes, int n_in,
                              void* d_out, int out_size, void* d_ws, size_t ws_size,
                              hipStream_t stream) {
  (void)in_sizes; (void)n_in; (void)out_size; (void)ws_size;
  const float* z = (const float*)d_in[0];
  const float* e = (const float*)d_in[1];
  float* out = (float*)d_out;
  char*  ws  = (char*)d_ws;

  int*          idx       = (int*)ws;
  unsigned int* hist      = (unsigned int*)(ws + 262144);
  double*       loss_part = (double*)(ws + 270336);
  float*        enorm     = (float*)(ws + 272384);
  int*          flag_cnt  = (int*)(ws + 280576);
  f16*          e_hi      = (f16*)(ws + 524288);
  f16*          e_lo      = (f16*)(ws + 1572864);

  // pass-2 scratch in d_out's z_q region (dead until gather)
  float* pval      = out + 32;
  int*   pidx      = (int*)(out + 32 + 1048576);
  int*   flag_list = (int*)(out + 32 + 2097152);

  float* out_zq  = out + 1;
  float* out_idx = out + 1 + (size_t)NROWS * DIM;

  prep_kernel<<<512, 256, 0, stream>>>(
      e, enorm, (short4*)e_hi, (short4*)e_lo, hist, loss_part, flag_cnt);
  pass1_kernel<<<NROWS / 64, 512, 0, stream>>>(
      z, e_hi, enorm, idx, hist, loss_part, flag_cnt, flag_list);
  pass2_kernel<<<512, 512, 0, stream>>>(
      z, e_hi, e_lo, enorm, flag_cnt, flag_list, pval, pidx);
  pass2m_kernel<<<64, 256, 0, stream>>>(
      flag_cnt, flag_list, pval, pidx, idx, hist, loss_part);
  gather_kernel<<<NROWS / 4, 256, 0, stream>>>(e, idx, out_zq, out_idx);
  finalize_kernel<<<1, 256, 0, stream>>>(hist, loss_part, out);
}